// Round 11
// baseline (36.463 us; speedup 1.0000x reference)
//
#include <hip/hip_runtime.h>

#define ROWF 84        // floats per output row (80 cls + 4 reg)

typedef float f32x4 __attribute__((ext_vector_type(4)));

// One block = one wave = 64 consecutive points of one image (levels are
// 64-aligned so the wave is level-uniform).
//  Phase 0: preload gt boxes into LDS; ballot-compact size-relevant gts
//           (ascending-g order preserved -> stable-sort tie semantics).
//  Phase 1: bulk-zero this block's 64x84-float output region with
//           sc0+sc1+nt global stores (system-scope, no-allocate ->
//           bypass the dirty-MALL allocate/evict path, stream to memory).
//  Phase 2: branchless min-score scan over ALL gts (argmin fallback),
//           overlapping the zero-store drain.
//  fence vmcnt(0)  -- bypassed zeros globally visible
//  Phase 3: per compacted gt: hit test; green -> atomicMax(out[p][label])
//           (fetches the zero from memory, RMWs coherently in L2).
//  fence vmcnt(0)
//  Phase 4: gray -1 overrides + reg float4 store (normal stores: must merge
//           with atomic-dirtied L2 lines). Row p touched only by thread p.
__global__ __launch_bounds__(64) void lfd_assign_kernel(
    const float* __restrict__ gt_bboxes,   // (B,G,4) x0,y0,w,h
    const int*   __restrict__ gt_labels,   // (B,G)
    const float* __restrict__ points,      // (P,2)
    const float* __restrict__ reg_ranges,  // (P,2)
    const float* __restrict__ gray_ranges, // (P,2)
    const float* __restrict__ strides,     // (P,)
    float* __restrict__ out,               // (B,P,84)
    int G, int P)
{
    extern __shared__ float lds[];
    float4*   boxA  = (float4*)lds;                      // [G] x0,y0,x1m1,y1m1
    float2*   ctr   = (float2*)(boxA + G);               // [G] cx,cy
    unsigned* clist = (unsigned*)(ctr + ((G + 1) & ~1)); // [G] compacted

    const int tid = threadIdx.x;
    const int b   = blockIdx.y;
    const int p   = blockIdx.x * 64 + tid;

    // --- per-point (wave-uniform level) constants ---
    const float px  = points[p * 2 + 0];
    const float py  = points[p * 2 + 1];
    const float lo  = reg_ranges[p * 2 + 0];
    const float up  = reg_ranges[p * 2 + 1];
    const float glo = gray_ranges[p * 2 + 0];
    const float gup = gray_ranges[p * 2 + 1];
    const float inv_half = 2.0f / strides[p];  // strides pow2 -> exact
    const float inv_up   = 1.0f / up;

    // --- phase 0: preload gts (slots g=tid, g=tid+64), classify ---
    bool i0 = false, gray0 = false, i1 = false, gray1 = false;
    int  lab0 = 0, lab1 = 0;
    {
        int g = tid;
        if (g < G) {
            const float4 bb = *(const float4*)(gt_bboxes + (size_t)(b * G + g) * 4);
            boxA[g] = make_float4(bb.x, bb.y, bb.x + bb.z - 1.0f, bb.y + bb.w - 1.0f);
            ctr[g]  = make_float2(bb.x + 0.5f * bb.z, bb.y + 0.5f * bb.w);
            const float larger = fmaxf(bb.z, bb.w);
            lab0 = gt_labels[b * G + g];
            const bool green = (lo <= larger) && (larger <= up);
            gray0 = ((glo <= larger) && (larger < lo)) || ((up < larger) && (larger <= gup));
            i0 = green || gray0;
        }
        g = tid + 64;
        if (g < G) {
            const float4 bb = *(const float4*)(gt_bboxes + (size_t)(b * G + g) * 4);
            boxA[g] = make_float4(bb.x, bb.y, bb.x + bb.z - 1.0f, bb.y + bb.w - 1.0f);
            ctr[g]  = make_float2(bb.x + 0.5f * bb.z, bb.y + 0.5f * bb.w);
            const float larger = fmaxf(bb.z, bb.w);
            lab1 = gt_labels[b * G + g];
            const bool green = (lo <= larger) && (larger <= up);
            gray1 = ((glo <= larger) && (larger < lo)) || ((up < larger) && (larger <= gup));
            i1 = green || gray1;
        }
    }
    // ballot-compaction (single wave; ascending-g order preserved)
    const unsigned long long m0 = __ballot(i0);
    const unsigned long long m1 = __ballot(i1);
    const int c0 = __popcll(m0);
    const unsigned long long below = (1ull << tid) - 1ull;
    if (i0) clist[__popcll(m0 & below)] =
        (unsigned)tid | ((unsigned)lab0 << 8) | (gray0 ? 0x80000000u : 0u);
    if (i1) clist[c0 + __popcll(m1 & below)] =
        (unsigned)(tid + 64) | ((unsigned)lab1 << 8) | (gray1 ? 0x80000000u : 0u);
    const int ncomp = c0 + __popcll(m1);

    // --- phase 1: bulk-zero the block's output region (bypass stores) ---
    f32x4* dst4 = (f32x4*)(out + (size_t)(b * P + blockIdx.x * 64) * ROWF);
    const f32x4 z4 = (f32x4){0.f, 0.f, 0.f, 0.f};
#pragma unroll
    for (int k = 0; k < 21; ++k) {
        const f32x4* addr = dst4 + k * 64 + tid;
        asm volatile("global_store_dwordx4 %0, %1, off sc0 sc1 nt"
                     :: "v"(addr), "v"(z4) : "memory");
    }

    // --- phase 2: branchless min-score scan over ALL gts (2 per b128) ---
    const float4* ctr2 = (const float4*)ctr;
    float min_score = 1e30f; int min_g = 0;
    int g = 0;
#pragma unroll 4
    for (; g + 1 < G; g += 2) {
        const float4 c = ctr2[g >> 1];
        const float s0 = rsqrtf(fmaxf(fabsf(px - c.x) * inv_half, 1.0f) *
                                fmaxf(fabsf(py - c.y) * inv_half, 1.0f));
        const float s1 = rsqrtf(fmaxf(fabsf(px - c.z) * inv_half, 1.0f) *
                                fmaxf(fabsf(py - c.w) * inv_half, 1.0f));
        if (s0 < min_score) { min_score = s0; min_g = g; }
        if (s1 < min_score) { min_score = s1; min_g = g + 1; }
    }
    if (g < G) {
        const float2 c = ctr[g];
        const float s0 = rsqrtf(fmaxf(fabsf(px - c.x) * inv_half, 1.0f) *
                                fmaxf(fabsf(py - c.y) * inv_half, 1.0f));
        if (s0 < min_score) { min_score = s0; min_g = g; }
    }

    // bypassed zeros must be globally visible before any same-address RMW
    asm volatile("s_waitcnt vmcnt(0)" ::: "memory");

    // --- phase 3: compacted gts: hit test, green atomicMax + best ---
    float* myout = out + (size_t)(b * P + p) * ROWF;
    float best_score = 0.0f; int best_g = 0;
    unsigned gm0 = 0u, gm1 = 0u, gm2 = 0u;
    for (int i = 0; i < ncomp; ++i) {
        const unsigned e = clist[i];
        const int gg = (int)(e & 0xFFu);
        const float4 A = boxA[gg];
        const float d1 = px - A.x, d2 = py - A.y, d3 = A.z - px, d4 = A.w - py;
        if (fminf(fminf(d1, d2), fminf(d3, d4)) >= 0.0f) {
            const int label = (int)((e >> 8) & 0x7Fu);
            if (e & 0x80000000u) {               // gray
                if (label < 32)      gm0 |= 1u << label;
                else if (label < 64) gm1 |= 1u << (label - 32);
                else                 gm2 |= 1u << (label - 64);
            } else {                              // green
                const float2 c = ctr[gg];
                const float s = rsqrtf(fmaxf(fabsf(px - c.x) * inv_half, 1.0f) *
                                       fmaxf(fabsf(py - c.y) * inv_half, 1.0f));
                // zeros visible; s>0 so int order == float order
                atomicMax((int*)(myout + label), __float_as_int(s));
                if (s > best_score) { best_score = s; best_g = gg; }
            }
        }
    }

    // own atomics must land before own gray -1 stores (same addresses)
    asm volatile("s_waitcnt vmcnt(0)" ::: "memory");

    // --- phase 4: gray overrides + reg store (row p touched only by thread p) ---
    unsigned t;
    t = gm0; while (t) { const int c = __ffs(t) - 1; myout[c]      = -1.0f; t &= t - 1u; }
    t = gm1; while (t) { const int c = __ffs(t) - 1; myout[32 + c] = -1.0f; t &= t - 1u; }
    t = gm2; while (t) { const int c = __ffs(t) - 1; myout[64 + c] = -1.0f; t &= t - 1u; }

    const int sel = (best_score > 0.0f) ? best_g : min_g;
    const float4 A = boxA[sel];
    *(float4*)(myout + 80) = make_float4((px - A.x) * inv_up, (py - A.y) * inv_up,
                                         (A.z - px) * inv_up, (A.w - py) * inv_up);
}

extern "C" void kernel_launch(void* const* d_in, const int* in_sizes, int n_in,
                              void* d_out, int out_size, void* d_ws, size_t ws_size,
                              hipStream_t stream) {
    const float* gt_bboxes   = (const float*)d_in[0];
    const int*   gt_labels   = (const int*)d_in[1];
    const float* points      = (const float*)d_in[2];
    const float* reg_ranges  = (const float*)d_in[3];
    const float* gray_ranges = (const float*)d_in[4];
    const float* strides     = (const float*)d_in[5];
    float* out = (float*)d_out;

    const int P = in_sizes[5];            // strides has P elements
    const int B = out_size / (P * ROWF);  // out is (B,P,84)
    const int G = in_sizes[1] / B;        // gt_labels is (B,G)  (G<=128 assumed)

    dim3 grid(P / 64, B);
    dim3 block(64);
    const size_t shmem = (size_t)G * sizeof(float4)               // boxA
                       + (size_t)((G + 1) & ~1) * sizeof(float2)  // ctr
                       + (size_t)G * sizeof(unsigned);            // clist
    lfd_assign_kernel<<<grid, block, shmem, stream>>>(
        gt_bboxes, gt_labels, points, reg_ranges, gray_ranges, strides, out, G, P);
}